// Round 3
// baseline (870.267 us; speedup 1.0000x reference)
//
#include <hip/hip_runtime.h>
#include <hip/hip_bf16.h>

// ---------------------------------------------------------------------------
// RelationalNetwork: N=32, C=24, H=W=14, O=196, HD=128, GH=256, AS=28
// pairs[n,i,j] = [feats[n,j](26), feats[n,i](26), code[n](128)]  (D_IN=180)
// h1 = relu(AJ'[n,j] + BI[n,i])        AJ' has CC (code-term) + gb0 folded in
// h  = relu(h@gw{1,2,3}+gb)            fused, bf16 MFMA 16x16x32, LDS-resident
// relations[n] = sum over 196^2 pairs  -> head MLP (fp32, tiny)
//
// Round 3: ROWS 128->64 (LDS 32KiB -> 3 blocks/CU, 24 waves/CU vs 16),
// acc[2][4], launch_bounds(512,7) (VGPR<=73), swizzle adds (row&8)<<2 to
// de-conflict epilogue b16 stores (q=0 vs q=2 collided with old swizzle).
// ---------------------------------------------------------------------------

typedef __attribute__((ext_vector_type(8))) short short8;
typedef __attribute__((ext_vector_type(4))) float f32x4;

#define NIMG 32
#define O 196
#define PAIRS 38416
#define GH 256
#define AS 28
#define ROWS 64
#define CHUNKS 601          // 600*64 + 16 = 38416 (tail chunk: 16 valid rows)

#define SWZ(row) ((((row) & 7) << 4) ^ (((row) & 8) << 2))

static __device__ __forceinline__ unsigned short f2bf(float f) {
    __hip_bfloat16 h = __float2bfloat16(f);
    return *reinterpret_cast<unsigned short*>(&h);
}

// ---- setup kernel B: CC[n,g] = code[n] @ gw0[52:180] + gb0 -----------------
__global__ void k_cc(const float* __restrict__ code, const float* __restrict__ gw0,
                     const float* __restrict__ gb0, float* __restrict__ CC) {
    const int n = blockIdx.x, g = threadIdx.x;
    __shared__ float cs[128];
    if (g < 128) cs[g] = code[n * 128 + g];
    __syncthreads();
    float acc = gb0[g];
    for (int k = 0; k < 128; ++k) acc = fmaf(cs[k], gw0[(52 + k) * GH + g], acc);
    CC[n * GH + g] = acc;
}

// ---- setup kernel A: AJ'[n,p,g] (includes CC), BI[n,p,g] -------------------
__global__ void k_ajbi(const float* __restrict__ x, const float* __restrict__ gw0,
                       const float* __restrict__ CC,
                       float* __restrict__ AJ, float* __restrict__ BI) {
    const int np = blockIdx.x;            // n*196 + p
    const int n = np / O, p = np - n * O;
    const int g = threadIdx.x;
    __shared__ float fs[26];
    if (g < 24)       fs[g]  = x[(n * 24 + g) * O + p];
    else if (g == 24) fs[24] = -7.0f + (float)(p / 14) * (14.0f / 13.0f);
    else if (g == 25) fs[25] = -7.0f + (float)(p % 14) * (14.0f / 13.0f);
    __syncthreads();
    float aj = CC[n * GH + g], bi = 0.f;
#pragma unroll
    for (int c = 0; c < 26; ++c) {
        const float f = fs[c];
        aj = fmaf(f, gw0[c * GH + g], aj);
        bi = fmaf(f, gw0[(26 + c) * GH + g], bi);
    }
    AJ[np * GH + g] = aj;
    BI[np * GH + g] = bi;
}

// ---- setup kernel C: pack gw1/2/3 into bf16 MFMA B-fragment layout ---------
// packed[((ntile*8+ks)*64+lane)*8+e] = W[ks*32+(lane>>4)*8+e][ntile*16+(lane&15)]
__global__ void k_pack(const float* __restrict__ gw1, const float* __restrict__ gw2,
                       const float* __restrict__ gw3, unsigned short* __restrict__ pW) {
    const int idx = blockIdx.x * 256 + threadIdx.x;     // 3*65536 total
    const int L = idx >> 16;
    const int rem = idx & 0xFFFF;
    const int e = rem & 7;
    const int lane = (rem >> 3) & 63;
    const int ks = (rem >> 9) & 7;
    const int ntile = rem >> 12;
    const int k = ks * 32 + ((lane >> 4) << 3) + e;
    const int col = ntile * 16 + (lane & 15);
    const float* W = (L == 0) ? gw1 : (L == 1) ? gw2 : gw3;
    pW[idx] = f2bf(W[k * GH + col]);
}

// ---- main fused kernel: h1 build + 3 GEMM layers + sum-pool ----------------
__global__ __launch_bounds__(512, 7) void k_main(
    const float* __restrict__ AJ, const float* __restrict__ BI,
    const unsigned short* __restrict__ pW,
    const float* __restrict__ gb1, const float* __restrict__ gb2,
    const float* __restrict__ gb3, float* __restrict__ rel) {
    // 64 rows x 256 cols bf16, XOR-swizzled: byte ^= SWZ(row). 32 KiB.
    __shared__ __attribute__((aligned(16))) unsigned short h[ROWS * GH];

    const int blk = blockIdx.x;           // n*601 + chunk
    const int n = blk / CHUNKS;
    const int chunk = blk - n * CHUNKS;
    const int row_base = chunk * ROWS;
    const int t = threadIdx.x;
    const int wave = t >> 6;              // 0..7
    const int lane = t & 63;
    const int l15 = lane & 15;
    const int q = lane >> 4;
    const int mh = wave >> 2;             // M half  (rows mh*32 .. +31)
    const int wq = wave & 3;              // N quarter (cols wq*64 .. +63)
    const bool tail = (chunk == CHUNKS - 1);

    // ---- phase 0: h1 = relu(AJ'[j] + BI[i]) -> LDS (bf16, swizzled) ----
    // Each wave: 8 rows (r = wave + 8e), 64 lanes x 4 cols = full 256-col row.
    {
        const int i0 = row_base / O;
        const int j00 = row_base - i0 * O;
        const int i1 = min(i0 + 1, O - 1);
        const float4 bi0 = *(const float4*)&BI[(n * O + i0) * GH + lane * 4];
        const float4 bi1 = *(const float4*)&BI[(n * O + i1) * GH + lane * 4];
#pragma unroll
        for (int e = 0; e < 8; ++e) {
            const int r = wave + e * 8;
            const int jj = j00 + r;                 // <= 195+63, one wrap max
            const bool wrap = (jj >= O);
            const int j = wrap ? jj - O : jj;       // tail garbage rows read
            const float4 aj = *(const float4*)&AJ[(n * O + j) * GH + lane * 4];
            const float4 bi = wrap ? bi1 : bi0;     // in-range rows; masked later
            const unsigned int lo = (unsigned)f2bf(fmaxf(aj.x + bi.x, 0.f)) |
                                    ((unsigned)f2bf(fmaxf(aj.y + bi.y, 0.f)) << 16);
            const unsigned int hi = (unsigned)f2bf(fmaxf(aj.z + bi.z, 0.f)) |
                                    ((unsigned)f2bf(fmaxf(aj.w + bi.w, 0.f)) << 16);
            const int byteoff = r * 512 + ((lane * 8) ^ SWZ(r));
            uint2 dd; dd.x = lo; dd.y = hi;
            *(uint2*)((char*)h + byteoff) = dd;
        }
    }
    __syncthreads();

    const float* gbs[3] = {gb1, gb2, gb3};
    const int X = SWZ(l15);                             // A-read swizzle (lane-const)
    const char* hb = (const char*)h + (mh * 32 + l15) * 512;
    const int cb2 = (wq * 64 + l15) * 2;                // epilogue col byte base

    for (int layer = 0; layer < 3; ++layer) {
        f32x4 acc[2][4];
#pragma unroll
        for (int mt = 0; mt < 2; ++mt)
#pragma unroll
            for (int nt = 0; nt < 4; ++nt) acc[mt][nt] = (f32x4){0.f, 0.f, 0.f, 0.f};

        const short8* wp = (const short8*)(pW + layer * 65536);
#pragma unroll 1
        for (int ks = 0; ks < 8; ++ks) {
            short8 b[4];
#pragma unroll
            for (int nt = 0; nt < 4; ++nt)
                b[nt] = wp[((wq * 4 + nt) * 8 + ks) * 64 + lane];
            const int off = (ks * 64 + q * 16) ^ X;     // swizzled k-offset
            short8 a[2];
#pragma unroll
            for (int mt = 0; mt < 2; ++mt)
                a[mt] = *(const short8*)(hb + off + mt * 8192);
#pragma unroll
            for (int mt = 0; mt < 2; ++mt)
#pragma unroll
                for (int nt = 0; nt < 4; ++nt)
                    acc[mt][nt] = __builtin_amdgcn_mfma_f32_16x16x32_bf16(
                        a[mt], b[nt], acc[mt][nt], 0, 0, 0);
        }
        __syncthreads();

        const float* gb = gbs[layer];
        if (layer < 2) {
            // bias + relu -> bf16 back to LDS (swizzled b16 stores)
#pragma unroll
            for (int nt = 0; nt < 4; ++nt) {
                const float bias = gb[wq * 64 + nt * 16 + l15];
#pragma unroll
                for (int r = 0; r < 4; ++r) {
                    const int rowl = q * 4 + r;
                    const int base = (mh * 32 + rowl) * 512 +
                                     ((cb2 + nt * 32) ^ SWZ(rowl));
#pragma unroll
                    for (int mt = 0; mt < 2; ++mt)
                        *(unsigned short*)((char*)h + base + mt * 8192) =
                            f2bf(fmaxf(acc[mt][nt][r] + bias, 0.0f));
                }
            }
            __syncthreads();
        } else {
            // final: bias + relu + column-sum (tail chunk: only rows 0..15 valid
            // = mh==0 && mt==0; wave-uniform mask)
#pragma unroll
            for (int nt = 0; nt < 4; ++nt) {
                const int col = wq * 64 + nt * 16 + l15;
                const float bias = gb[col];
                float s = 0.f;
#pragma unroll
                for (int mt = 0; mt < 2; ++mt) {
                    if (tail && !(mh == 0 && mt == 0)) continue;
#pragma unroll
                    for (int r = 0; r < 4; ++r)
                        s += fmaxf(acc[mt][nt][r] + bias, 0.0f);
                }
                s += __shfl_xor(s, 16);
                s += __shfl_xor(s, 32);
                if (q == 0) atomicAdd(&rel[n * GH + col], s);
            }
        }
    }
}

// ---- head MLP (fp32, tiny): relations -> logits ----------------------------
__global__ void k_fmlp(const float* __restrict__ rel,
                       const float* __restrict__ fw0, const float* __restrict__ fb0,
                       const float* __restrict__ fw1, const float* __restrict__ fb1,
                       const float* __restrict__ fw2, const float* __restrict__ fb2,
                       float* __restrict__ out) {
    __shared__ float b0[GH], b1[GH];
    const int n = blockIdx.x, g = threadIdx.x;
    b0[g] = rel[n * GH + g];
    __syncthreads();
    float a = fb0[g];
    for (int k = 0; k < GH; ++k) a = fmaf(b0[k], fw0[k * GH + g], a);
    b1[g] = fmaxf(a, 0.f);
    __syncthreads();
    float c = fb1[g];
    for (int k = 0; k < GH; ++k) c = fmaf(b1[k], fw1[k * GH + g], c);
    b0[g] = fmaxf(c, 0.f);
    __syncthreads();
    if (g < AS) {
        float o = fb2[g];
        for (int k = 0; k < GH; ++k) o = fmaf(b0[k], fw2[k * AS + g], o);
        out[n * AS + g] = o;
    }
}

// ---------------------------------------------------------------------------
extern "C" void kernel_launch(void* const* d_in, const int* in_sizes, int n_in,
                              void* d_out, int out_size, void* d_ws, size_t ws_size,
                              hipStream_t stream) {
    const float* x    = (const float*)d_in[0];
    const float* code = (const float*)d_in[1];
    const float* gw0  = (const float*)d_in[2];
    const float* gb0  = (const float*)d_in[3];
    const float* gw1  = (const float*)d_in[4];
    const float* gb1  = (const float*)d_in[5];
    const float* gw2  = (const float*)d_in[6];
    const float* gb2  = (const float*)d_in[7];
    const float* gw3  = (const float*)d_in[8];
    const float* gb3  = (const float*)d_in[9];
    const float* fw0  = (const float*)d_in[10];
    const float* fb0  = (const float*)d_in[11];
    const float* fw1  = (const float*)d_in[12];
    const float* fb1  = (const float*)d_in[13];
    const float* fw2  = (const float*)d_in[14];
    const float* fb2  = (const float*)d_in[15];
    float* out = (float*)d_out;

    char* ws = (char*)d_ws;
    // workspace layout (16B aligned)
    float*          AJ  = (float*)(ws + 0);                 // 32*196*256*4 = 6,422,528
    float*          BI  = (float*)(ws + 6422528);           // 6,422,528
    float*          CC  = (float*)(ws + 12845056);          // 32,768
    float*          rel = (float*)(ws + 12877824);          // 32,768
    unsigned short* pW  = (unsigned short*)(ws + 12910592); // 3*65536*2 = 393,216

    hipMemsetAsync(rel, 0, NIMG * GH * sizeof(float), stream);
    k_cc<<<NIMG, 256, 0, stream>>>(code, gw0, gb0, CC);
    k_ajbi<<<NIMG * O, 256, 0, stream>>>(x, gw0, CC, AJ, BI);
    k_pack<<<3 * 256, 256, 0, stream>>>(gw1, gw2, gw3, pW);
    k_main<<<NIMG * CHUNKS, 512, 0, stream>>>(AJ, BI, pW, gb1, gb2, gb3, rel);
    k_fmlp<<<NIMG, 256, 0, stream>>>(rel, fw0, fb0, fw1, fb1, fw2, fb2, out);
}

// Round 4
// 616.834 us; speedup vs baseline: 1.4109x; 1.4109x over previous
//
#include <hip/hip_runtime.h>
#include <hip/hip_bf16.h>

// ---------------------------------------------------------------------------
// RelationalNetwork: N=32, C=24, H=W=14, O=196, HD=128, GH=256, AS=28
// pairs[n,i,j] = [feats[n,j](26), feats[n,i](26), code[n](128)]  (D_IN=180)
// h1 = relu(AJ'[n,j] + BI[n,i])        AJ' has CC (code-term) + gb0 folded in
// h  = relu(h@gw{1,2,3}+gb)            fused, bf16 MFMA, LDS-resident
// relations[n] = sum over 196^2 pairs  -> head MLP (fp32, tiny)
//
// Round 4: 32x32x16 MFMA (half the MFMA instrs of 16x16x32), wave tiling
// 1M x 8N (each wave owns a 32-col slice -> zero weight duplication across
// waves: 384 KB L2/block, was 768), ROWS=96 (48 KiB LDS -> 3 blocks/CU),
// launch_bounds(512,5) = 102-reg cap (round 3's (512,7)=73 cap caused a
// 1.5 GB/dispatch scratch-spill disaster; acc=48 AGPR + ~45 VGPR fits 102).
// ---------------------------------------------------------------------------

typedef __attribute__((ext_vector_type(8))) short short8;
typedef __attribute__((ext_vector_type(16))) float f32x16;

#define NIMG 32
#define O 196
#define PAIRS 38416
#define GH 256
#define AS 28
#define ROWS 96
#define CHUNKS 401          // 400*96 + 16 = 38416 (tail chunk: 16 valid rows)

#define SWZ(row) ((((row) & 7) << 4) ^ (((row) & 8) << 2))

static __device__ __forceinline__ unsigned short f2bf(float f) {
    __hip_bfloat16 h = __float2bfloat16(f);
    return *reinterpret_cast<unsigned short*>(&h);
}

// ---- setup kernel B: CC[n,g] = code[n] @ gw0[52:180] + gb0 -----------------
__global__ void k_cc(const float* __restrict__ code, const float* __restrict__ gw0,
                     const float* __restrict__ gb0, float* __restrict__ CC) {
    const int n = blockIdx.x, g = threadIdx.x;
    __shared__ float cs[128];
    if (g < 128) cs[g] = code[n * 128 + g];
    __syncthreads();
    float acc = gb0[g];
    for (int k = 0; k < 128; ++k) acc = fmaf(cs[k], gw0[(52 + k) * GH + g], acc);
    CC[n * GH + g] = acc;
}

// ---- setup kernel A: AJ'[n,p,g] (includes CC), BI[n,p,g] -------------------
__global__ void k_ajbi(const float* __restrict__ x, const float* __restrict__ gw0,
                       const float* __restrict__ CC,
                       float* __restrict__ AJ, float* __restrict__ BI) {
    const int np = blockIdx.x;            // n*196 + p
    const int n = np / O, p = np - n * O;
    const int g = threadIdx.x;
    __shared__ float fs[26];
    if (g < 24)       fs[g]  = x[(n * 24 + g) * O + p];
    else if (g == 24) fs[24] = -7.0f + (float)(p / 14) * (14.0f / 13.0f);
    else if (g == 25) fs[25] = -7.0f + (float)(p % 14) * (14.0f / 13.0f);
    __syncthreads();
    float aj = CC[n * GH + g], bi = 0.f;
#pragma unroll
    for (int c = 0; c < 26; ++c) {
        const float f = fs[c];
        aj = fmaf(f, gw0[c * GH + g], aj);
        bi = fmaf(f, gw0[(26 + c) * GH + g], bi);
    }
    AJ[np * GH + g] = aj;
    BI[np * GH + g] = bi;
}

// ---- setup kernel C: pack gw1/2/3 into 32x32x16 B-fragment layout ----------
// elem offset = L*65536 + nt*8192 + ks*512 + lane*8 + e
// value = W[ks*16 + (lane>>5)*8 + e][nt*32 + (lane&31)]
__global__ void k_pack(const float* __restrict__ gw1, const float* __restrict__ gw2,
                       const float* __restrict__ gw3, unsigned short* __restrict__ pW) {
    const int idx = blockIdx.x * 256 + threadIdx.x;     // 3*65536 total
    const int L = idx >> 16;
    const int rem = idx & 0xFFFF;
    const int e = rem & 7;
    const int lane = (rem >> 3) & 63;
    const int ks = (rem >> 9) & 15;
    const int nt = rem >> 13;                            // 0..7 (= wave)
    const int k = ks * 16 + ((lane >> 5) << 3) + e;
    const int col = nt * 32 + (lane & 31);
    const float* W = (L == 0) ? gw1 : (L == 1) ? gw2 : gw3;
    pW[idx] = f2bf(W[k * GH + col]);
}

// ---- main fused kernel: h1 build + 3 GEMM layers + sum-pool ----------------
__global__ __launch_bounds__(512, 5) void k_main(
    const float* __restrict__ AJ, const float* __restrict__ BI,
    const unsigned short* __restrict__ pW,
    const float* __restrict__ gb1, const float* __restrict__ gb2,
    const float* __restrict__ gb3, float* __restrict__ rel) {
    // 96 rows x 256 cols bf16, XOR-swizzled: byte ^= SWZ(row). 48 KiB.
    __shared__ __attribute__((aligned(16))) unsigned short h[ROWS * GH];

    const int blk = blockIdx.x;           // n*401 + chunk
    const int n = blk / CHUNKS;
    const int chunk = blk - n * CHUNKS;
    const int row_base = chunk * ROWS;
    const int t = threadIdx.x;
    const int wave = t >> 6;              // 0..7  (= N-slice, cols wave*32..+31)
    const int lane = t & 63;
    const int l31 = lane & 31;
    const int hi = lane >> 5;
    const int l15 = lane & 15;
    const bool tail = (chunk == CHUNKS - 1);

    // ---- phase 0: h1 = relu(AJ'[j] + BI[i]) -> LDS (bf16, swizzled) ----
    // Each wave writes 12 rows (r = wave + 8e), full 256-col row per iter.
    {
        const int i0 = row_base / O;
        const int j00 = row_base - i0 * O;
        const int i1 = min(i0 + 1, O - 1);
        const float4 bi0 = *(const float4*)&BI[(n * O + i0) * GH + lane * 4];
        const float4 bi1 = *(const float4*)&BI[(n * O + i1) * GH + lane * 4];
#pragma unroll
        for (int e = 0; e < 12; ++e) {
            const int r = wave + e * 8;
            const int jj = j00 + r;                 // one wrap max
            const bool wrap = (jj >= O);
            const int j = wrap ? jj - O : jj;       // tail garbage rows; masked later
            const float4 aj = *(const float4*)&AJ[(n * O + j) * GH + lane * 4];
            const float4 bi = wrap ? bi1 : bi0;
            const unsigned int lo = (unsigned)f2bf(fmaxf(aj.x + bi.x, 0.f)) |
                                    ((unsigned)f2bf(fmaxf(aj.y + bi.y, 0.f)) << 16);
            const unsigned int hh = (unsigned)f2bf(fmaxf(aj.z + bi.z, 0.f)) |
                                    ((unsigned)f2bf(fmaxf(aj.w + bi.w, 0.f)) << 16);
            const int byteoff = r * 512 + ((lane * 8) ^ SWZ(r));
            uint2 dd; dd.x = lo; dd.y = hh;
            *(uint2*)((char*)h + byteoff) = dd;
        }
    }
    __syncthreads();

    const float* gbs[3] = {gb1, gb2, gb3};
    const int X = SWZ(l15);               // lane-const: row&15 == l15 for A-reads
    const int arow = l31 * 512;           // A-read row byte base (row = mt*32+l31)
    const int hi16 = hi << 4;
    const char* hB = (const char*)h;

    for (int layer = 0; layer < 3; ++layer) {
        f32x16 acc0 = {0.f,0.f,0.f,0.f,0.f,0.f,0.f,0.f,0.f,0.f,0.f,0.f,0.f,0.f,0.f,0.f};
        f32x16 acc1 = acc0, acc2 = acc0;

        // wave's weight slice: 16 KiB contiguous (cols wave*32..+31, all K)
        const short8* wp = (const short8*)(pW + layer * 65536 + wave * 8192);
        short8 b0 = wp[0 * 64 + lane];
        short8 b1 = wp[1 * 64 + lane];
#pragma unroll
        for (int ks = 0; ks < 16; ++ks) {
            const short8 b = b0;
            b0 = b1;
            if (ks < 14) b1 = wp[(ks + 2) * 64 + lane];
            const int off = (ks * 32 + hi16) ^ X;       // swizzled k byte offset
            const short8 a0 = *(const short8*)(hB + arow + off);
            const short8 a1 = *(const short8*)(hB + arow + off + 16384);
            const short8 a2 = *(const short8*)(hB + arow + off + 32768);
            acc0 = __builtin_amdgcn_mfma_f32_32x32x16_bf16(a0, b, acc0, 0, 0, 0);
            acc1 = __builtin_amdgcn_mfma_f32_32x32x16_bf16(a1, b, acc1, 0, 0, 0);
            acc2 = __builtin_amdgcn_mfma_f32_32x32x16_bf16(a2, b, acc2, 0, 0, 0);
        }
        __syncthreads();

        const float bias = gbs[layer][wave * 32 + l31];
        if (layer < 2) {
            // bias + relu -> bf16 back to LDS (swizzled b16 stores)
            // C layout 32x32: col=lane&31, row=(r&3)+8*(r>>2)+4*hi
            const int colb = (wave * 32 + l31) * 2;
#pragma unroll
            for (int r = 0; r < 16; ++r) {
                const int rr = (r & 3) + 8 * (r >> 2) + 4 * hi;
                const int swz = colb ^ SWZ(rr);
                *(unsigned short*)((char*)h + (rr      ) * 512 + swz) =
                    f2bf(fmaxf(acc0[r] + bias, 0.0f));
                *(unsigned short*)((char*)h + (rr +  32) * 512 + swz) =
                    f2bf(fmaxf(acc1[r] + bias, 0.0f));
                *(unsigned short*)((char*)h + (rr +  64) * 512 + swz) =
                    f2bf(fmaxf(acc2[r] + bias, 0.0f));
            }
            __syncthreads();
        } else {
            // final: bias + relu + column-sum; lanes (l, l+32) share a column.
            // tail chunk: valid rows 0..15 = acc0 regs 0..7 (rows (r&3)+8*(r>>2)+4hi < 16)
            float s = 0.f;
            if (!tail) {
#pragma unroll
                for (int r = 0; r < 16; ++r)
                    s += fmaxf(acc0[r] + bias, 0.0f) +
                         fmaxf(acc1[r] + bias, 0.0f) +
                         fmaxf(acc2[r] + bias, 0.0f);
            } else {
#pragma unroll
                for (int r = 0; r < 8; ++r)
                    s += fmaxf(acc0[r] + bias, 0.0f);
            }
            s += __shfl_xor(s, 32);
            if (hi == 0) atomicAdd(&rel[n * GH + wave * 32 + l31], s);
        }
    }
}

// ---- head MLP (fp32, tiny): relations -> logits ----------------------------
__global__ void k_fmlp(const float* __restrict__ rel,
                       const float* __restrict__ fw0, const float* __restrict__ fb0,
                       const float* __restrict__ fw1, const float* __restrict__ fb1,
                       const float* __restrict__ fw2, const float* __restrict__ fb2,
                       float* __restrict__ out) {
    __shared__ float b0[GH], b1[GH];
    const int n = blockIdx.x, g = threadIdx.x;
    b0[g] = rel[n * GH + g];
    __syncthreads();
    float a = fb0[g];
    for (int k = 0; k < GH; ++k) a = fmaf(b0[k], fw0[k * GH + g], a);
    b1[g] = fmaxf(a, 0.f);
    __syncthreads();
    float c = fb1[g];
    for (int k = 0; k < GH; ++k) c = fmaf(b1[k], fw1[k * GH + g], c);
    b0[g] = fmaxf(c, 0.f);
    __syncthreads();
    if (g < AS) {
        float o = fb2[g];
        for (int k = 0; k < GH; ++k) o = fmaf(b0[k], fw2[k * AS + g], o);
        out[n * AS + g] = o;
    }
}

// ---------------------------------------------------------------------------
extern "C" void kernel_launch(void* const* d_in, const int* in_sizes, int n_in,
                              void* d_out, int out_size, void* d_ws, size_t ws_size,
                              hipStream_t stream) {
    const float* x    = (const float*)d_in[0];
    const float* code = (const float*)d_in[1];
    const float* gw0  = (const float*)d_in[2];
    const float* gb0  = (const float*)d_in[3];
    const float* gw1  = (const float*)d_in[4];
    const float* gb1  = (const float*)d_in[5];
    const float* gw2  = (const float*)d_in[6];
    const float* gb2  = (const float*)d_in[7];
    const float* gw3  = (const float*)d_in[8];
    const float* gb3  = (const float*)d_in[9];
    const float* fw0  = (const float*)d_in[10];
    const float* fb0  = (const float*)d_in[11];
    const float* fw1  = (const float*)d_in[12];
    const float* fb1  = (const float*)d_in[13];
    const float* fw2  = (const float*)d_in[14];
    const float* fb2  = (const float*)d_in[15];
    float* out = (float*)d_out;

    char* ws = (char*)d_ws;
    // workspace layout (16B aligned)
    float*          AJ  = (float*)(ws + 0);                 // 32*196*256*4 = 6,422,528
    float*          BI  = (float*)(ws + 6422528);           // 6,422,528
    float*          CC  = (float*)(ws + 12845056);          // 32,768
    float*          rel = (float*)(ws + 12877824);          // 32,768
    unsigned short* pW  = (unsigned short*)(ws + 12910592); // 3*65536*2 = 393,216

    hipMemsetAsync(rel, 0, NIMG * GH * sizeof(float), stream);
    k_cc<<<NIMG, 256, 0, stream>>>(code, gw0, gb0, CC);
    k_ajbi<<<NIMG * O, 256, 0, stream>>>(x, gw0, CC, AJ, BI);
    k_pack<<<768, 256, 0, stream>>>(gw1, gw2, gw3, pW);
    k_main<<<NIMG * CHUNKS, 512, 0, stream>>>(AJ, BI, pW, gb1, gb2, gb3, rel);
    k_fmlp<<<NIMG, 256, 0, stream>>>(rel, fw0, fb0, fw1, fb1, fw2, fb2, out);
}

// Round 5
// 563.663 us; speedup vs baseline: 1.5439x; 1.0943x over previous
//
#include <hip/hip_runtime.h>
#include <hip/hip_bf16.h>

// ---------------------------------------------------------------------------
// RelationalNetwork: N=32, C=24, H=W=14, O=196, HD=128, GH=256, AS=28
// pairs[n,i,j] = [feats[n,j](26), feats[n,i](26), code[n](128)]  (D_IN=180)
// h1 = relu(AJ'[n,j] + BI[n,i])        AJ' has CC (code-term) + gb0 folded in
// h  = relu(h@gw{1,2,3}+gb)            fused, bf16 MFMA 32x32x16, LDS-resident
// relations[n] = sum over 196^2 pairs  -> head MLP (fp32, tiny)
//
// Round 5: spill fix. Register-file model (measured r2-r4): total VGPR+AGPR
// budget per wave = 512 / launch_bounds_waves. (512,5)=102 forced the
// compiler to spill an accumulator (577 MB/dispatch scratch writes = the
// whole kernel time). acc[3]=48 AGPR demands ~100 total -> only (512,4)=128
// is spill-free. 512-thread blocks place 2 waves/SIMD, so blocks/CU =
// floor(cap_waves/2): (512,5) gave no occupancy over (512,4) anyway.
// Keep: 32x32x16 MFMA, 1M x 8N wave tiling (no weight dup), ROWS=96.
// ---------------------------------------------------------------------------

typedef __attribute__((ext_vector_type(8))) short short8;
typedef __attribute__((ext_vector_type(16))) float f32x16;

#define NIMG 32
#define O 196
#define PAIRS 38416
#define GH 256
#define AS 28
#define ROWS 96
#define CHUNKS 401          // 400*96 + 16 = 38416 (tail chunk: 16 valid rows)

#define SWZ(row) ((((row) & 7) << 4) ^ (((row) & 8) << 2))

static __device__ __forceinline__ unsigned short f2bf(float f) {
    __hip_bfloat16 h = __float2bfloat16(f);
    return *reinterpret_cast<unsigned short*>(&h);
}

// ---- setup kernel B: CC[n,g] = code[n] @ gw0[52:180] + gb0 -----------------
__global__ void k_cc(const float* __restrict__ code, const float* __restrict__ gw0,
                     const float* __restrict__ gb0, float* __restrict__ CC) {
    const int n = blockIdx.x, g = threadIdx.x;
    __shared__ float cs[128];
    if (g < 128) cs[g] = code[n * 128 + g];
    __syncthreads();
    float acc = gb0[g];
    for (int k = 0; k < 128; ++k) acc = fmaf(cs[k], gw0[(52 + k) * GH + g], acc);
    CC[n * GH + g] = acc;
}

// ---- setup kernel A: AJ'[n,p,g] (includes CC), BI[n,p,g] -------------------
__global__ void k_ajbi(const float* __restrict__ x, const float* __restrict__ gw0,
                       const float* __restrict__ CC,
                       float* __restrict__ AJ, float* __restrict__ BI) {
    const int np = blockIdx.x;            // n*196 + p
    const int n = np / O, p = np - n * O;
    const int g = threadIdx.x;
    __shared__ float fs[26];
    if (g < 24)       fs[g]  = x[(n * 24 + g) * O + p];
    else if (g == 24) fs[24] = -7.0f + (float)(p / 14) * (14.0f / 13.0f);
    else if (g == 25) fs[25] = -7.0f + (float)(p % 14) * (14.0f / 13.0f);
    __syncthreads();
    float aj = CC[n * GH + g], bi = 0.f;
#pragma unroll
    for (int c = 0; c < 26; ++c) {
        const float f = fs[c];
        aj = fmaf(f, gw0[c * GH + g], aj);
        bi = fmaf(f, gw0[(26 + c) * GH + g], bi);
    }
    AJ[np * GH + g] = aj;
    BI[np * GH + g] = bi;
}

// ---- setup kernel C: pack gw1/2/3 into 32x32x16 B-fragment layout ----------
// elem offset = L*65536 + nt*8192 + ks*512 + lane*8 + e
// value = W[ks*16 + (lane>>5)*8 + e][nt*32 + (lane&31)]
__global__ void k_pack(const float* __restrict__ gw1, const float* __restrict__ gw2,
                       const float* __restrict__ gw3, unsigned short* __restrict__ pW) {
    const int idx = blockIdx.x * 256 + threadIdx.x;     // 3*65536 total
    const int L = idx >> 16;
    const int rem = idx & 0xFFFF;
    const int e = rem & 7;
    const int lane = (rem >> 3) & 63;
    const int ks = (rem >> 9) & 15;
    const int nt = rem >> 13;                            // 0..7 (= wave)
    const int k = ks * 16 + ((lane >> 5) << 3) + e;
    const int col = nt * 32 + (lane & 31);
    const float* W = (L == 0) ? gw1 : (L == 1) ? gw2 : gw3;
    pW[idx] = f2bf(W[k * GH + col]);
}

// ---- main fused kernel: h1 build + 3 GEMM layers + sum-pool ----------------
__global__ __launch_bounds__(512, 4) void k_main(
    const float* __restrict__ AJ, const float* __restrict__ BI,
    const unsigned short* __restrict__ pW,
    const float* __restrict__ gb1, const float* __restrict__ gb2,
    const float* __restrict__ gb3, float* __restrict__ rel) {
    // 96 rows x 256 cols bf16, XOR-swizzled: byte ^= SWZ(row). 48 KiB.
    __shared__ __attribute__((aligned(16))) unsigned short h[ROWS * GH];

    const int blk = blockIdx.x;           // n*401 + chunk
    const int n = blk / CHUNKS;
    const int chunk = blk - n * CHUNKS;
    const int row_base = chunk * ROWS;
    const int t = threadIdx.x;
    const int wave = t >> 6;              // 0..7  (= N-slice, cols wave*32..+31)
    const int lane = t & 63;
    const int l31 = lane & 31;
    const int hi = lane >> 5;
    const int l15 = lane & 15;
    const bool tail = (chunk == CHUNKS - 1);

    // ---- phase 0: h1 = relu(AJ'[j] + BI[i]) -> LDS (bf16, swizzled) ----
    // Each wave writes 12 rows (r = wave + 8e), full 256-col row per iter.
    {
        const int i0 = row_base / O;
        const int j00 = row_base - i0 * O;
        const int i1 = min(i0 + 1, O - 1);
        const float4 bi0 = *(const float4*)&BI[(n * O + i0) * GH + lane * 4];
        const float4 bi1 = *(const float4*)&BI[(n * O + i1) * GH + lane * 4];
#pragma unroll
        for (int e = 0; e < 12; ++e) {
            const int r = wave + e * 8;
            const int jj = j00 + r;                 // one wrap max
            const bool wrap = (jj >= O);
            const int j = wrap ? jj - O : jj;       // tail garbage rows; masked later
            const float4 aj = *(const float4*)&AJ[(n * O + j) * GH + lane * 4];
            const float4 bi = wrap ? bi1 : bi0;
            const unsigned int lo = (unsigned)f2bf(fmaxf(aj.x + bi.x, 0.f)) |
                                    ((unsigned)f2bf(fmaxf(aj.y + bi.y, 0.f)) << 16);
            const unsigned int hh = (unsigned)f2bf(fmaxf(aj.z + bi.z, 0.f)) |
                                    ((unsigned)f2bf(fmaxf(aj.w + bi.w, 0.f)) << 16);
            const int byteoff = r * 512 + ((lane * 8) ^ SWZ(r));
            uint2 dd; dd.x = lo; dd.y = hh;
            *(uint2*)((char*)h + byteoff) = dd;
        }
    }
    __syncthreads();

    const float* gbs[3] = {gb1, gb2, gb3};
    const int X = SWZ(l15);               // lane-const: row&15 == l15 for A-reads
    const int arow = l31 * 512;           // A-read row byte base (row = mt*32+l31)
    const int hi16 = hi << 4;
    const char* hB = (const char*)h;

    for (int layer = 0; layer < 3; ++layer) {
        f32x16 acc0 = {0.f,0.f,0.f,0.f,0.f,0.f,0.f,0.f,0.f,0.f,0.f,0.f,0.f,0.f,0.f,0.f};
        f32x16 acc1 = acc0, acc2 = acc0;

        // wave's weight slice: 16 KiB contiguous (cols wave*32..+31, all K)
        const short8* wp = (const short8*)(pW + layer * 65536 + wave * 8192);
        short8 b0 = wp[0 * 64 + lane];
        short8 b1 = wp[1 * 64 + lane];
#pragma unroll
        for (int ks = 0; ks < 16; ++ks) {
            const short8 b = b0;
            b0 = b1;
            if (ks < 14) b1 = wp[(ks + 2) * 64 + lane];
            const int off = (ks * 32 + hi16) ^ X;       // swizzled k byte offset
            const short8 a0 = *(const short8*)(hB + arow + off);
            const short8 a1 = *(const short8*)(hB + arow + off + 16384);
            const short8 a2 = *(const short8*)(hB + arow + off + 32768);
            acc0 = __builtin_amdgcn_mfma_f32_32x32x16_bf16(a0, b, acc0, 0, 0, 0);
            acc1 = __builtin_amdgcn_mfma_f32_32x32x16_bf16(a1, b, acc1, 0, 0, 0);
            acc2 = __builtin_amdgcn_mfma_f32_32x32x16_bf16(a2, b, acc2, 0, 0, 0);
        }
        __syncthreads();

        const float bias = gbs[layer][wave * 32 + l31];
        if (layer < 2) {
            // bias + relu -> bf16 back to LDS (swizzled b16 stores)
            // C layout 32x32: col=lane&31, row=(r&3)+8*(r>>2)+4*hi
            const int colb = (wave * 32 + l31) * 2;
#pragma unroll
            for (int r = 0; r < 16; ++r) {
                const int rr = (r & 3) + 8 * (r >> 2) + 4 * hi;
                const int swz = colb ^ SWZ(rr);
                *(unsigned short*)((char*)h + (rr      ) * 512 + swz) =
                    f2bf(fmaxf(acc0[r] + bias, 0.0f));
                *(unsigned short*)((char*)h + (rr +  32) * 512 + swz) =
                    f2bf(fmaxf(acc1[r] + bias, 0.0f));
                *(unsigned short*)((char*)h + (rr +  64) * 512 + swz) =
                    f2bf(fmaxf(acc2[r] + bias, 0.0f));
            }
            __syncthreads();
        } else {
            // final: bias + relu + column-sum; lanes (l, l+32) share a column.
            // tail chunk: valid rows 0..15 = acc0 regs 0..7 (rows (r&3)+8*(r>>2)+4hi < 16)
            float s = 0.f;
            if (!tail) {
#pragma unroll
                for (int r = 0; r < 16; ++r)
                    s += fmaxf(acc0[r] + bias, 0.0f) +
                         fmaxf(acc1[r] + bias, 0.0f) +
                         fmaxf(acc2[r] + bias, 0.0f);
            } else {
#pragma unroll
                for (int r = 0; r < 8; ++r)
                    s += fmaxf(acc0[r] + bias, 0.0f);
            }
            s += __shfl_xor(s, 32);
            if (hi == 0) atomicAdd(&rel[n * GH + wave * 32 + l31], s);
        }
    }
}

// ---- head MLP (fp32, tiny): relations -> logits ----------------------------
__global__ void k_fmlp(const float* __restrict__ rel,
                       const float* __restrict__ fw0, const float* __restrict__ fb0,
                       const float* __restrict__ fw1, const float* __restrict__ fb1,
                       const float* __restrict__ fw2, const float* __restrict__ fb2,
                       float* __restrict__ out) {
    __shared__ float b0[GH], b1[GH];
    const int n = blockIdx.x, g = threadIdx.x;
    b0[g] = rel[n * GH + g];
    __syncthreads();
    float a = fb0[g];
    for (int k = 0; k < GH; ++k) a = fmaf(b0[k], fw0[k * GH + g], a);
    b1[g] = fmaxf(a, 0.f);
    __syncthreads();
    float c = fb1[g];
    for (int k = 0; k < GH; ++k) c = fmaf(b1[k], fw1[k * GH + g], c);
    b0[g] = fmaxf(c, 0.f);
    __syncthreads();
    if (g < AS) {
        float o = fb2[g];
        for (int k = 0; k < GH; ++k) o = fmaf(b0[k], fw2[k * AS + g], o);
        out[n * AS + g] = o;
    }
}

// ---------------------------------------------------------------------------
extern "C" void kernel_launch(void* const* d_in, const int* in_sizes, int n_in,
                              void* d_out, int out_size, void* d_ws, size_t ws_size,
                              hipStream_t stream) {
    const float* x    = (const float*)d_in[0];
    const float* code = (const float*)d_in[1];
    const float* gw0  = (const float*)d_in[2];
    const float* gb0  = (const float*)d_in[3];
    const float* gw1  = (const float*)d_in[4];
    const float* gb1  = (const float*)d_in[5];
    const float* gw2  = (const float*)d_in[6];
    const float* gb2  = (const float*)d_in[7];
    const float* gw3  = (const float*)d_in[8];
    const float* gb3  = (const float*)d_in[9];
    const float* fw0  = (const float*)d_in[10];
    const float* fb0  = (const float*)d_in[11];
    const float* fw1  = (const float*)d_in[12];
    const float* fb1  = (const float*)d_in[13];
    const float* fw2  = (const float*)d_in[14];
    const float* fb2  = (const float*)d_in[15];
    float* out = (float*)d_out;

    char* ws = (char*)d_ws;
    // workspace layout (16B aligned)
    float*          AJ  = (float*)(ws + 0);                 // 32*196*256*4 = 6,422,528
    float*          BI  = (float*)(ws + 6422528);           // 6,422,528
    float*          CC  = (float*)(ws + 12845056);          // 32,768
    float*          rel = (float*)(ws + 12877824);          // 32,768
    unsigned short* pW  = (unsigned short*)(ws + 12910592); // 3*65536*2 = 393,216

    hipMemsetAsync(rel, 0, NIMG * GH * sizeof(float), stream);
    k_cc<<<NIMG, 256, 0, stream>>>(code, gw0, gb0, CC);
    k_ajbi<<<NIMG * O, 256, 0, stream>>>(x, gw0, CC, AJ, BI);
    k_pack<<<768, 256, 0, stream>>>(gw1, gw2, gw3, pW);
    k_main<<<NIMG * CHUNKS, 512, 0, stream>>>(AJ, BI, pW, gb1, gb2, gb3, rel);
    k_fmlp<<<NIMG, 256, 0, stream>>>(rel, fw0, fb0, fw1, fb1, fw2, fb2, out);
}